// Round 11
// baseline (131.178 us; speedup 1.0000x reference)
//
#include <hip/hip_runtime.h>

// ASG loss, B=128 T=4000 N=64 L=101.
// R11: R10's math verbatim; prefetch pipelines rebuilt.
//  Num: per step needs em[t][y0(l)], em[t][y1(l)] for all 64 lanes = the
//   whole 64-float row. Load rows COALESCED (1 global_load_dword per row,
//   lane = column), redistribute via 2 variable __shfl (bpermute) and
//   pre-exp2 in the prefetch phase. 16-step epochs, 3 raw buffers in a
//   statically unrolled 3-phase rotation: vmcnt wait lands 3 epochs
//   (~48 steps) after issue, 48 loads in flight. Chain = dpp+fma+mul.
//  Den: E-prefetch deepened 4->6 SUBs; renorm cadence 6 (static slot).
// Telescoped segmented scan (R4-R10) and combine unchanged.

#define TT 4000
#define NN 64
#define LL 101
#define NSEG 32

static constexpr float L2E  = 1.44269504088896340736f;   // log2(e)
static constexpr float LN2F = 0.69314718055994530942f;
static constexpr float NEG2 = -1.0e30f;

// ws layout (floats)
#define WS_X    0                      // [128][NSEG] per-segment log2 ratios
#define WS_NF   4096                   // [128][112] fwd numer (log2)
#define WS_HB   18432                  // [128][112] bwd numer (log2)
#define WS_LOSS 32768                  // [128] per-batch loss

#if defined(__has_builtin)
#if __has_builtin(__builtin_amdgcn_mfma_f32_16x16x16bf16_1k)
#define BF16MM 1
#endif
#if __has_builtin(__builtin_amdgcn_exp2f)
#define FEXP2(x) __builtin_amdgcn_exp2f(x)
#endif
#if __has_builtin(__builtin_amdgcn_logf)
#define FLOG2(x) __builtin_amdgcn_logf(x)
#endif
#endif
#ifndef FEXP2
#define FEXP2(x) exp2f(x)
#endif
#ifndef FLOG2
#define FLOG2(x) log2f(x)
#endif

typedef float f32x4 __attribute__((ext_vector_type(4)));
typedef short s16x4 __attribute__((ext_vector_type(4)));
typedef _Float16 h4 __attribute__((ext_vector_type(4)));

// bf16 pack, round-to-nearest-even, pure C (no asm)
__device__ __forceinline__ unsigned cvt2(float a, float b) {
#ifdef BF16MM
  const unsigned ua = __builtin_bit_cast(unsigned, a);
  const unsigned ub = __builtin_bit_cast(unsigned, b);
  const unsigned ra = (ua + 0x7FFFu + ((ua >> 16) & 1u)) >> 16;
  const unsigned rb = (ub + 0x7FFFu + ((ub >> 16) & 1u)) >> 16;
  return ra | (rb << 16);
#else
  return __builtin_bit_cast(unsigned,
      __builtin_amdgcn_cvt_pkrtz(fminf(a, 3.0e4f), fminf(b, 3.0e4f)));
#endif
}

__device__ __forceinline__ f32x4 MM(uint2 a, uint2 b, f32x4 c) {
#ifdef BF16MM
  return __builtin_amdgcn_mfma_f32_16x16x16bf16_1k(
      __builtin_bit_cast(s16x4, a), __builtin_bit_cast(s16x4, b), c, 0, 0, 0);
#else
  return __builtin_amdgcn_mfma_f32_16x16x16f16(
      __builtin_bit_cast(h4, a), __builtin_bit_cast(h4, b), c, 0, 0, 0);
#endif
}

// DPP lane shift: 0x138 = wave_shr:1, 0x130 = wave_shl:1 (boundary reads 0).
template<int CTRL>
__device__ __forceinline__ float dppf(float x) {
  return __builtin_bit_cast(float, __builtin_amdgcn_update_dpp(
      0, __builtin_bit_cast(int, x), CTRL, 0xf, 0xf, true));
}

// ---------------- numerator chain (R10 math, pipelined delivery) -----------
template<int DIR>
__device__ __forceinline__ void num_chain(const float* __restrict__ em,
                                          const float* __restrict__ TR,
                                          const int* __restrict__ Y,
                                          float* __restrict__ ws,
                                          const int b, const int l)
{
  const bool v0 = (2 * l     <= 100);
  const bool v1 = (2 * l + 1 <= 100);
  const int k0 = v0 ? 2 * l     : 100;
  const int k1 = v1 ? 2 * l + 1 : 100;
  const int y0 = Y[b * LL + k0];
  const int y1 = Y[b * LL + k1];
  const float SW0 = v0 ? FEXP2(TR[(y0 + 1) * NN + y0] * L2E) : 0.f;
  const float SW1 = v1 ? FEXP2(TR[(y1 + 1) * NN + y1] * L2E) : 0.f;
  float WLOC, WRECV, B0, B1, C;
  bool recvok;
  if (DIR == 0) {
    WLOC = v1 ? FEXP2(TR[(y1 + 1) * NN + y0] * L2E) : 0.f;
    const int ym0 = Y[b * LL + (k0 > 0 ? k0 - 1 : 0)];
    recvok = v0 && (l > 0);
    WRECV = recvok ? FEXP2(TR[(y0 + 1) * NN + ym0] * L2E) : 0.f;
    B0 = (l == 0) ? 1.f : 0.f;
    B1 = 0.f;
    C  = (l == 0) ? (TR[y0] + em[y0]) * L2E : 0.f;
  } else {
    WLOC = v1 ? FEXP2(TR[(y1 + 1) * NN + y0] * L2E) : 0.f;
    const int kp = (2 * l + 2 <= 100) ? 2 * l + 2 : 100;
    const int yp1 = Y[b * LL + kp];
    recvok = (2 * l + 2 <= 100);
    WRECV = recvok ? FEXP2(TR[(yp1 + 1) * NN + y1] * L2E) : 0.f;
    B0 = (l == 50) ? 1.f : 0.f;
    B1 = 0.f;
    C  = (l == 50) ? em[(size_t)(TT - 1) * NN + y0] * L2E : 0.f;
  }

#define TROW(t) ((size_t)((DIR == 0) ? (t) : (TT - 1 - (t))) * NN)

  float RA[16], RB[16], RC[16];        // raw rows (3 epochs deep)
  float PC0[16], PC1[16];              // processed exp2 pairs, current epoch
  float PN0[16], PN1[16];              // processed pairs, next epoch
  float ADJ = 0.f;

  // epoch e covers steps t = 1+16e+k, k=0..15 (clamped at 1999)
#define ISSUE(R, e)                                                            \
  { _Pragma("unroll") for (int k_ = 0; k_ < 16; ++k_) {                        \
      int t_ = 1 + 16 * (e) + k_; t_ = (t_ < 1999) ? t_ : 1999;                \
      R[k_] = em[TROW(t_) + l]; } }

#define PROC(P0, P1, R)                                                        \
  { _Pragma("unroll") for (int k_ = 0; k_ < 16; ++k_) {                        \
      const float r_ = R[k_];                                                  \
      const float a_ = __shfl(r_, y0);                                         \
      const float b_ = __shfl(r_, y1);                                         \
      P0[k_] = FEXP2(a_ * L2E);                                                \
      P1[k_] = FEXP2(b_ * L2E); } }

#define COPYP()                                                                \
  { _Pragma("unroll") for (int k_ = 0; k_ < 16; ++k_) {                        \
      PC0[k_] = PN0[k_]; PC1[k_] = PN1[k_]; } }

#define RESCALE()                                                              \
  {                                                                            \
    const float v_ = B0 + B1;                                                  \
    const int bits_ = __builtin_bit_cast(int, v_);                             \
    const int m_ = (v_ > 0.f) ? ((bits_ >> 23) & 255) - 127 : 0;               \
    const float sc_ = __builtin_bit_cast(float, (127 - m_) << 23);             \
    B0 *= sc_; B1 *= sc_; C += (float)m_;                                      \
    const float Cn_ = dppf<(DIR == 0) ? 0x138 : 0x130>(C);                     \
    const float dC_ = fminf(fmaxf(Cn_ - C, -120.f), 120.f);                    \
    ADJ = recvok ? FEXP2(dC_) * WRECV : 0.f;                                   \
  }

#define NSTEP2(E0v, E1v)                                                       \
  {                                                                            \
    if (DIR == 0) {                                                            \
      const float NB = dppf<0x138>(B1);                                        \
      const float t0 = fmaf(NB, ADJ, B0 * SW0);                                \
      const float t1 = fmaf(B0, WLOC, B1 * SW1);                               \
      B0 = t0 * (E0v); B1 = t1 * (E1v);                                        \
    } else {                                                                   \
      const float NB = dppf<0x130>(B0);                                        \
      const float t1 = fmaf(NB, ADJ, B1 * SW1);                                \
      const float t0 = fmaf(B1, WLOC, B0 * SW0);                               \
      B0 = t0 * (E0v); B1 = t1 * (E1v);                                        \
    }                                                                          \
  }

#define RUN16()                                                                \
  { RESCALE();                                                                 \
    _Pragma("unroll") for (int k_ = 0; k_ < 8; ++k_)                           \
      NSTEP2(PC0[k_], PC1[k_]);                                                \
    RESCALE();                                                                 \
    _Pragma("unroll") for (int k_ = 8; k_ < 16; ++k_)                          \
      NSTEP2(PC0[k_], PC1[k_]); }

#define PHASE(e, Rslot)                                                        \
  { RUN16();                                                                   \
    COPYP();                                                                   \
    PROC(PN0, PN1, Rslot);                                                     \
    ISSUE(Rslot, (e) + 5); }

  // prologue: fill pipeline
  ISSUE(RA, 0); ISSUE(RB, 1); ISSUE(RC, 2);
  PROC(PC0, PC1, RA);  ISSUE(RA, 3);
  PROC(PN0, PN1, RB);  ISSUE(RB, 4);

  // main: 41 supers x 3 epochs = epochs 0..122 (t = 1..1968)
  for (int s = 0; s < 41; ++s) {
    const int e = 3 * s;
    PHASE(e,     RC);
    PHASE(e + 1, RA);
    PHASE(e + 2, RB);
  }
  // epoch 123 (t = 1969..1984)
  RUN16();
  COPYP();                              // pairs of epoch 124
  // epoch 124, 15 steps (t = 1985..1999)
  RESCALE();
#pragma unroll
  for (int k_ = 0; k_ < 8; ++k_) NSTEP2(PC0[k_], PC1[k_]);
  RESCALE();
#pragma unroll
  for (int k_ = 8; k_ < 15; ++k_) NSTEP2(PC0[k_], PC1[k_]);

#undef PHASE
#undef RUN16
#undef NSTEP2
#undef RESCALE
#undef COPYP
#undef PROC
#undef ISSUE
#undef TROW

  const float o0 = (B0 > 1e-37f) ? C + FLOG2(B0) : NEG2;
  const float o1 = (B1 > 1e-37f) ? C + FLOG2(B1) : NEG2;
  const int base = (DIR ? WS_HB : WS_NF) + b * 112;
  if (v0) ws[base + 2 * l]     = o0;
  if (v1) ws[base + 2 * l + 1] = o1;
}

__global__ __launch_bounds__(128) void asg_main(
    const float* __restrict__ E, const float* __restrict__ TR,
    const int* __restrict__ Y, float* __restrict__ ws)
{
  const int bid  = blockIdx.x;
  const int w    = threadIdx.x >> 6;
  const int lane = threadIdx.x & 63;
  const int b    = bid >> 1;
  const float* em = E + (size_t)b * TT * NN;

  if (w == 0) {
    // ================= denominator: 16 segments via MFMA (R10 math) ======
    const int h = bid & 1;
    const int c = lane & 15, g = lane >> 4;
    const int j = h * 16 + c;                 // segment 0..31

    uint2 Af[4][4];
#pragma unroll
    for (int rt = 0; rt < 4; ++rt)
#pragma unroll
      for (int kt = 0; kt < 4; ++kt) {
        const float* tr = TR + (size_t)(16 * rt + c + 1) * NN + 16 * kt + 4 * g;
        const float w0 = FEXP2(tr[0] * L2E), w1 = FEXP2(tr[1] * L2E);
        const float w2 = FEXP2(tr[2] * L2E), w3 = FEXP2(tr[3] * L2E);
        Af[rt][kt].x = cvt2(w0, w1);
        Af[rt][kt].y = cvt2(w2, w3);
      }

    f32x4 P[4];
#pragma unroll
    for (int rt = 0; rt < 4; ++rt)
#pragma unroll
      for (int e = 0; e < 4; ++e) {
        const int row = 16 * rt + 4 * g + e;
        P[rt][e] = (j == 0) ? FEXP2((em[row] + TR[row]) * L2E) : 1.0f;
      }

    float Csum = 0.f, snap31 = 0.f;
    const float* ebase = em + (size_t)(124 * j + 1) * NN + 4 * g;

#define COLSUM(dst) { float t_ =                                               \
      (P[0].x + P[0].y + P[0].z + P[0].w) + (P[1].x + P[1].y + P[1].z + P[1].w)\
    + (P[2].x + P[2].y + P[2].z + P[2].w) + (P[3].x + P[3].y + P[3].z + P[3].w);\
    t_ += __shfl_xor(t_, 16); t_ += __shfl_xor(t_, 32);                        \
    (dst) = fmaxf(t_, 1e-30f); }

#define RENORM() { float cs_; COLSUM(cs_);                                     \
    const int mb_ = ((__builtin_bit_cast(int, cs_) >> 23) & 255) - 127;        \
    const float sc_ = __builtin_bit_cast(float, (127 - mb_) << 23);            \
    P[0] *= sc_; P[1] *= sc_; P[2] *= sc_; P[3] *= sc_;                        \
    Csum += (float)mb_; }

#define ELOAD(D, s_) { const int se_ = (s_) < 154 ? (s_) : 154;                \
    const f32x4* p_ = (const f32x4*)(ebase + (size_t)se_ * NN);                \
    D[0] = p_[0]; D[1] = p_[4]; D[2] = p_[8]; D[3] = p_[12]; }

#define STEP(M)                                                                \
    {                                                                          \
      uint2 Bf[4];                                                             \
      _Pragma("unroll") for (int kt = 0; kt < 4; ++kt) {                       \
        Bf[kt].x = cvt2(P[kt].x, P[kt].y);                                     \
        Bf[kt].y = cvt2(P[kt].z, P[kt].w);                                     \
      }                                                                        \
      _Pragma("unroll") for (int rt = 0; rt < 4; ++rt) {                       \
        f32x4 acc = {0.f, 0.f, 0.f, 0.f};                                      \
        acc = MM(Af[rt][0], Bf[0], acc);                                       \
        acc = MM(Af[rt][1], Bf[1], acc);                                       \
        acc = MM(Af[rt][2], Bf[2], acc);                                       \
        acc = MM(Af[rt][3], Bf[3], acc);                                       \
        _Pragma("unroll") for (int e = 0; e < 4; ++e)                          \
          P[rt][e] = fminf(fmaxf(                                              \
              acc[e] * FEXP2(fmaf(M[rt][e], L2E, -6.7f)), 1e-20f), 1e25f);     \
      }                                                                        \
    }

    // kr = position within the 6-group (renorm at kr==5, static)
#define SUB(Ebuf, ss, kr)                                                      \
    { f32x4 T_[4] = {Ebuf[0], Ebuf[1], Ebuf[2], Ebuf[3]};                      \
      ELOAD(Ebuf, (ss) + 6);                                                   \
      STEP(T_);                                                                \
      if ((ss) == 30) { float cs2_; COLSUM(cs2_);                              \
                        snap31 = Csum + FLOG2(cs2_) + 6.7f * 31.f; }           \
      if ((kr) == 5) RENORM(); }

    f32x4 E0[4], E1[4], E2[4], E3[4], E4[4], E5[4];
    ELOAD(E0, 0); ELOAD(E1, 1); ELOAD(E2, 2);
    ELOAD(E3, 3); ELOAD(E4, 4); ELOAD(E5, 5);

    for (int it = 0; it < 25; ++it) {        // steps s = 0..149
      const int s = 6 * it;
      SUB(E0, s, 0);     SUB(E1, s + 1, 1); SUB(E2, s + 2, 2);
      SUB(E3, s + 3, 3); SUB(E4, s + 4, 4); SUB(E5, s + 5, 5);
    }
    // tail s = 150..154 (buffers already hold these rows)
    { f32x4 T_[4] = {E0[0], E0[1], E0[2], E0[3]}; STEP(T_); }
    { f32x4 T_[4] = {E1[0], E1[1], E1[2], E1[3]}; STEP(T_); }
    { f32x4 T_[4] = {E2[0], E2[1], E2[2], E2[3]}; STEP(T_); }
    { f32x4 T_[4] = {E3[0], E3[1], E3[2], E3[3]}; STEP(T_); }
    { f32x4 T_[4] = {E4[0], E4[1], E4[2], E4[3]}; STEP(T_); }

    float csf; COLSUM(csf);
    const float fin = Csum + FLOG2(csf) + 6.7f * 155.f;
    const float X = fin - ((j == 0) ? 0.f : snap31);
    if (lane < 16) ws[WS_X + b * NSEG + (h * 16 + lane)] = X;

#undef SUB
#undef STEP
#undef ELOAD
#undef RENORM
#undef COLSUM

  } else {
    // ================= numerator ==========================================
    const int dir = bid & 1;
    if (dir == 0) num_chain<0>(em, TR, Y, ws, b, lane);
    else          num_chain<1>(em, TR, Y, ws, b, lane);
  }
}

__global__ __launch_bounds__(128) void asg_combine(
    const float* __restrict__ TR, const int* __restrict__ Y,
    const float* __restrict__ ws, float* __restrict__ lossv)
{
  const int b = blockIdx.x;
  const int tid = threadIdx.x;
  __shared__ float sN[LL], sH[LL], red[128];
  __shared__ float sLogZ;

  if (tid == 0) {
    float z = 0.f;
    for (int s = 0; s < NSEG; ++s) z += ws[WS_X + b * NSEG + s];
    sLogZ = z;                              // log2 Z
  }
  if (tid < LL) { sN[tid] = ws[WS_NF + b * 112 + tid]; sH[tid] = ws[WS_HB + b * 112 + tid]; }
  __syncthreads();

  float val2 = -3.0e38f;
  if (tid < LL) {
    const int l = tid;
    const int y = Y[b * LL + l];
    const float s1 = sN[l] + TR[(y + 1) * NN + y] * L2E;
    float s2 = NEG2;
    if (l > 0) {
      const int ymm = Y[b * LL + l - 1];
      s2 = sN[l - 1] + TR[(y + 1) * NN + ymm] * L2E;
    }
    const float m = fmaxf(s1, s2);
    val2 = m + log2f(exp2f(s1 - m) + exp2f(s2 - m)) + sH[l];
  }
  red[tid] = val2;
  __syncthreads();
  if (tid == 0) {
    float m = red[0];
    for (int k = 1; k < LL; ++k) m = fmaxf(m, red[k]);
    float s = 0.f;
    for (int k = 0; k < LL; ++k) s += exp2f(red[k] - m);
    const float tgt2 = m + log2f(s);
    lossv[b] = (sLogZ - tgt2) * LN2F / (float)LL;
  }
}

__global__ __launch_bounds__(64) void asg_reduce(const float* __restrict__ lossv,
                                                 float* __restrict__ out)
{
  const int tid = threadIdx.x;
  float v = lossv[tid] + lossv[tid + 64];
  for (int off = 32; off; off >>= 1) v += __shfl_xor(v, off);
  if (tid == 0) out[0] = v * (1.0f / 128.0f);
}

extern "C" void kernel_launch(void* const* d_in, const int* in_sizes, int n_in,
                              void* d_out, int out_size, void* d_ws, size_t ws_size,
                              hipStream_t stream) {
  const float* E  = (const float*)d_in[0];
  const float* TR = (const float*)d_in[1];
  const int*   Y  = (const int*)d_in[2];
  float* out = (float*)d_out;
  float* ws  = (float*)d_ws;
  float* lossv = ws + WS_LOSS;

  // 256 blocks x 2 waves: wave0 = den (16 MFMA segments), wave1 = num chain.
  asg_main<<<dim3(256), dim3(128), 0, stream>>>(E, TR, Y, ws);
  asg_combine<<<dim3(128), dim3(128), 0, stream>>>(TR, Y, ws, lossv);
  asg_reduce<<<dim3(1), dim3(64), 0, stream>>>(lossv, out);
}